// Round 1
// baseline (329.524 us; speedup 1.0000x reference)
//
#include <hip/hip_runtime.h>
#include <stdint.h>

// GraphConvLayer: 3x { x = X@W^T + b; x = Ahat @ x; x *= mask; x = gelu(x) }
// B=32, N=1024, D=256. Split-bf16 (hi/lo) MFMA for f32-grade accuracy.

typedef __attribute__((ext_vector_type(8))) short short8;   // 8 bf16 (4 VGPRs)
typedef __attribute__((ext_vector_type(4))) float f32x4;    // MFMA acc

__device__ __forceinline__ uint16_t f2bf(float f) {
  uint32_t u = __float_as_uint(f);
  u += 0x7FFF + ((u >> 16) & 1);          // RNE
  return (uint16_t)(u >> 16);
}
__device__ __forceinline__ float bf2f(uint16_t h) {
  return __uint_as_float(((uint32_t)h) << 16);
}
__device__ __forceinline__ float gelu_exact(float v) {
  return 0.5f * v * (1.0f + erff(v * 0.70710678118654752f));
}
__device__ __forceinline__ f32x4 mfma16(short8 a, short8 b, f32x4 c) {
  return __builtin_amdgcn_mfma_f32_16x16x32_bf16(a, b, c, 0, 0, 0);
}

#define GLD16(gsrc, ldst) __builtin_amdgcn_global_load_lds(                    \
    (const __attribute__((address_space(1))) void*)(gsrc),                     \
    (__attribute__((address_space(3))) void*)(ldst), 16, 0, 0)

// ---------------- split f32 -> bf16 hi/lo ----------------
__global__ void k_split(const float* __restrict__ src, uint16_t* __restrict__ h,
                        uint16_t* __restrict__ l, int n4) {
  int i = blockIdx.x * blockDim.x + threadIdx.x;
  if (i >= n4) return;
  const float4 v = ((const float4*)src)[i];
  float vv[4] = {v.x, v.y, v.z, v.w};
  ushort4 hh, ll;
  uint16_t* hp = (uint16_t*)&hh;
  uint16_t* lp = (uint16_t*)&ll;
#pragma unroll
  for (int e = 0; e < 4; ++e) {
    uint16_t hb = f2bf(vv[e]);
    hp[e] = hb;
    lp[e] = f2bf(vv[e] - bf2f(hb));
  }
  ((ushort4*)h)[i] = hh;
  ((ushort4*)l)[i] = ll;
}

// ---------------- row-normalize adj -> bf16 ----------------
// one block per (b,n) row of 1024
__global__ void k_norm_adj(const float* __restrict__ adj, uint16_t* __restrict__ An) {
  const int r = blockIdx.x;       // 0..32767
  const int t = threadIdx.x;      // 0..255
  const float* row = adj + (size_t)r * 1024;
  const float4 v = *(const float4*)(row + t * 4);
  float s = v.x + v.y + v.z + v.w;
#pragma unroll
  for (int off = 32; off; off >>= 1) s += __shfl_down(s, off);
  __shared__ float ws[4];
  if ((t & 63) == 0) ws[t >> 6] = s;
  __syncthreads();
  const float deg = ws[0] + ws[1] + ws[2] + ws[3];
  const float dinv = (deg != 0.f) ? 1.f / deg : 0.f;
  ushort4 o;
  uint16_t* op = (uint16_t*)&o;
  float vv[4] = {v.x, v.y, v.z, v.w};
#pragma unroll
  for (int e = 0; e < 4; ++e) op[e] = f2bf(vv[e] * dinv);
  *(ushort4*)(An + (size_t)r * 1024 + t * 4) = o;
}

// ---------------- linear: Yt = (X @ W^T + b), split, transposed ----------------
// X: [32768,256] bf16 hi/lo.  W: [256,256] bf16 hi/lo (row-major out x in).
// Out: Yth/Ytl [32][256 feat][1024 node] bf16.
// 3-term: Xh*Wh + Xh*Wl + Xl*Wh.
__global__ __launch_bounds__(256) void k_linear(
    const uint16_t* __restrict__ Xh, const uint16_t* __restrict__ Xl,
    const uint16_t* __restrict__ Wh, const uint16_t* __restrict__ Wl,
    const float* __restrict__ bias,
    uint16_t* __restrict__ Yth, uint16_t* __restrict__ Ytl) {
  __shared__ __align__(16) uint8_t smem[32768];  // Ah|Al|Wh|Wl tiles, 8KB each
  const int tid = threadIdx.x;
  const int lane = tid & 63;
  const int wave = tid >> 6;
  const int wr = wave >> 1, wc = wave & 1;
  const int m0 = blockIdx.x * 128;   // global row (b*1024+node)
  const int n0 = blockIdx.y * 128;   // out-feature
  const int lm = lane & 15, g = lane >> 4;
  const int srow = lane >> 2;        // staging: row within 16-row chunk
  const int skof = (lane & 3) * 8;   // staging: k element offset

  f32x4 acc[4][4] = {};

  for (int kt = 0; kt < 8; ++kt) {
    const int k0 = kt * 32;
    __syncthreads();
#pragma unroll
    for (int j = 0; j < 8; ++j) {
      const int c = j * 4 + wave;    // 0..31
      const int sub = c & 7, which = c >> 3;
      const int row = sub * 16 + srow;
      const uint16_t* src;
      if (which == 0)      src = Xh + (size_t)(m0 + row) * 256 + k0 + skof;
      else if (which == 1) src = Xl + (size_t)(m0 + row) * 256 + k0 + skof;
      else if (which == 2) src = Wh + (size_t)(n0 + row) * 256 + k0 + skof;
      else                 src = Wl + (size_t)(n0 + row) * 256 + k0 + skof;
      GLD16(src, smem + c * 1024);
    }
    asm volatile("s_waitcnt vmcnt(0)" ::: "memory");
    __syncthreads();

    const uint8_t* Ahs = smem;
    const uint8_t* Als = smem + 8192;
    const uint8_t* Bhs = smem + 16384;
    const uint8_t* Bls = smem + 24576;
    short8 ah[4], al[4], bh[4], bl[4];
#pragma unroll
    for (int f = 0; f < 4; ++f) {
      ah[f] = *(const short8*)(Ahs + (wr * 64 + f * 16 + lm) * 64 + g * 16);
      al[f] = *(const short8*)(Als + (wr * 64 + f * 16 + lm) * 64 + g * 16);
      bh[f] = *(const short8*)(Bhs + (wc * 64 + f * 16 + lm) * 64 + g * 16);
      bl[f] = *(const short8*)(Bls + (wc * 64 + f * 16 + lm) * 64 + g * 16);
    }
#pragma unroll
    for (int fm = 0; fm < 4; ++fm)
#pragma unroll
      for (int fn = 0; fn < 4; ++fn) {
        acc[fm][fn] = mfma16(ah[fm], bh[fn], acc[fm][fn]);
        acc[fm][fn] = mfma16(ah[fm], bl[fn], acc[fm][fn]);
        acc[fm][fn] = mfma16(al[fm], bh[fn], acc[fm][fn]);
      }
  }

  // epilogue: +bias, hi/lo split, store transposed (feat-major, node fast)
#pragma unroll
  for (int fn = 0; fn < 4; ++fn) {
    const int n = n0 + wc * 64 + fn * 16 + lm;
    const float bv = bias[n];
#pragma unroll
    for (int fm = 0; fm < 4; ++fm) {
      const int mg = m0 + wr * 64 + fm * 16 + g * 4;  // 4 consecutive global rows
      const int bb = mg >> 10, node = mg & 1023;
      ushort4 hh, ll;
      uint16_t* hp = (uint16_t*)&hh;
      uint16_t* lp = (uint16_t*)&ll;
#pragma unroll
      for (int e = 0; e < 4; ++e) {
        const float v = acc[fm][fn][e] + bv;
        const uint16_t hb = f2bf(v);
        hp[e] = hb;
        lp[e] = f2bf(v - bf2f(hb));
      }
      const size_t o = ((size_t)(bb * 256 + n)) * 1024 + node;
      *(ushort4*)(Yth + o) = hh;
      *(ushort4*)(Ytl + o) = ll;
    }
  }
}

// ---------------- aggregate: Z = An[b] @ Y, mask, gelu ----------------
// An: [32][1024][1024] bf16.  Yt: [32][256 feat][1024 node] bf16 hi/lo.
// 2-term: An*Yh + An*Yl.  Output row-major [b*1024+node][feat].
template <bool LAST>
__global__ __launch_bounds__(256) void k_agg(
    const uint16_t* __restrict__ An,
    const uint16_t* __restrict__ Yth, const uint16_t* __restrict__ Ytl,
    const float* __restrict__ mask,
    uint16_t* __restrict__ Xh, uint16_t* __restrict__ Xl,
    float* __restrict__ out) {
  __shared__ __align__(16) uint8_t smem[24576];  // A|Bh|Bl tiles, 8KB each
  const int tid = threadIdx.x;
  const int lane = tid & 63;
  const int wave = tid >> 6;
  const int wr = wave >> 1, wc = wave & 1;
  const int m0 = blockIdx.x * 128;   // node (out) within batch
  const int n0 = blockIdx.y * 128;   // feature
  const int b = blockIdx.z;
  const int lm = lane & 15, g = lane >> 4;
  const int srow = lane >> 2;
  const int skof = (lane & 3) * 8;
  const uint16_t* Ab  = An  + (size_t)b * 1024 * 1024;
  const uint16_t* Yhb = Yth + (size_t)b * 256 * 1024;
  const uint16_t* Ylb = Ytl + (size_t)b * 256 * 1024;

  f32x4 acc[4][4] = {};

  for (int kt = 0; kt < 32; ++kt) {
    const int k0 = kt * 32;
    __syncthreads();
#pragma unroll
    for (int j = 0; j < 6; ++j) {
      const int c = j * 4 + wave;    // 0..23
      const int sub = c & 7, which = c >> 3;
      const int row = sub * 16 + srow;
      const uint16_t* src;
      if (which == 0)      src = Ab  + (size_t)(m0 + row) * 1024 + k0 + skof;
      else if (which == 1) src = Yhb + (size_t)(n0 + row) * 1024 + k0 + skof;
      else                 src = Ylb + (size_t)(n0 + row) * 1024 + k0 + skof;
      GLD16(src, smem + c * 1024);
    }
    asm volatile("s_waitcnt vmcnt(0)" ::: "memory");
    __syncthreads();

    const uint8_t* As  = smem;
    const uint8_t* Bhs = smem + 8192;
    const uint8_t* Bls = smem + 16384;
    short8 a[4], bh[4], bl[4];
#pragma unroll
    for (int f = 0; f < 4; ++f) {
      a[f]  = *(const short8*)(As  + (wr * 64 + f * 16 + lm) * 64 + g * 16);
      bh[f] = *(const short8*)(Bhs + (wc * 64 + f * 16 + lm) * 64 + g * 16);
      bl[f] = *(const short8*)(Bls + (wc * 64 + f * 16 + lm) * 64 + g * 16);
    }
#pragma unroll
    for (int fm = 0; fm < 4; ++fm)
#pragma unroll
      for (int fn = 0; fn < 4; ++fn) {
        acc[fm][fn] = mfma16(a[fm], bh[fn], acc[fm][fn]);
        acc[fm][fn] = mfma16(a[fm], bl[fn], acc[fm][fn]);
      }
  }

  // epilogue: mask (per out-node), exact gelu, store
  const float* mb = mask + b * 1024;
#pragma unroll
  for (int fm = 0; fm < 4; ++fm) {
    const int m = m0 + wr * 64 + fm * 16 + g * 4;
    float mk[4];
#pragma unroll
    for (int e = 0; e < 4; ++e) mk[e] = mb[m + e];
#pragma unroll
    for (int fn = 0; fn < 4; ++fn) {
      const int n = n0 + wc * 64 + fn * 16 + lm;
#pragma unroll
      for (int e = 0; e < 4; ++e) {
        const float v = gelu_exact(acc[fm][fn][e] * mk[e]);
        const size_t o = ((size_t)(b * 1024 + m + e)) * 256 + n;
        if (LAST) {
          out[o] = v;
        } else {
          const uint16_t hb = f2bf(v);
          Xh[o] = hb;
          Xl[o] = f2bf(v - bf2f(hb));
        }
      }
    }
  }
}

extern "C" void kernel_launch(void* const* d_in, const int* in_sizes, int n_in,
                              void* d_out, int out_size, void* d_ws, size_t ws_size,
                              hipStream_t stream) {
  const float* x    = (const float*)d_in[0];
  const float* mask = (const float*)d_in[1];
  const float* adj  = (const float*)d_in[2];
  const float* W[3]  = {(const float*)d_in[3], (const float*)d_in[5], (const float*)d_in[7]};
  const float* bs[3] = {(const float*)d_in[4], (const float*)d_in[6], (const float*)d_in[8]};

  uint8_t* ws = (uint8_t*)d_ws;
  uint16_t* An  = (uint16_t*)(ws);                    // 32*1024*1024*2 = 67108864
  uint16_t* Xh  = (uint16_t*)(ws + 67108864);         // 16777216
  uint16_t* Xl  = (uint16_t*)(ws + 83886080);         // 16777216
  uint16_t* Yth = (uint16_t*)(ws + 100663296);        // 16777216
  uint16_t* Ytl = (uint16_t*)(ws + 117440512);        // 16777216
  uint16_t* Wh  = (uint16_t*)(ws + 134217728);        // 3*65536*2 = 393216
  uint16_t* Wl  = (uint16_t*)(ws + 134610944);        // 393216  (total ~128.8 MiB)

  // prologue: split x, split weights, normalize adjacency
  k_split<<<dim3(8192), 256, 0, stream>>>(x, Xh, Xl, 2097152);
  for (int i = 0; i < 3; ++i)
    k_split<<<dim3(64), 256, 0, stream>>>(W[i], Wh + i * 65536, Wl + i * 65536, 16384);
  k_norm_adj<<<dim3(32768), 256, 0, stream>>>(adj, An);

  for (int l = 0; l < 3; ++l) {
    k_linear<<<dim3(256, 2), 256, 0, stream>>>(Xh, Xl, Wh + l * 65536, Wl + l * 65536,
                                               bs[l], Yth, Ytl);
    if (l < 2)
      k_agg<false><<<dim3(8, 2, 32), 256, 0, stream>>>(An, Yth, Ytl, mask, Xh, Xl, nullptr);
    else
      k_agg<true><<<dim3(8, 2, 32), 256, 0, stream>>>(An, Yth, Ytl, mask, nullptr, nullptr,
                                                      (float*)d_out);
  }
}

// Round 2
// 257.096 us; speedup vs baseline: 1.2817x; 1.2817x over previous
//
#include <hip/hip_runtime.h>
#include <stdint.h>

// GraphConvLayer: 3x { x = X@W^T + b; x = Ahat @ x; x *= mask; x = gelu(x) }
// B=32, N=1024, D=256. Split-bf16 (hi/lo) MFMA for f32-grade accuracy.
// R2: k_agg rebuilt as 4-phase counted-vmcnt pipeline (T3+T4+T5), BN=256,
//     3-buffer LDS depth-2 prefetch, 1 block/CU.

typedef __attribute__((ext_vector_type(8))) short short8;   // 8 bf16 (4 VGPRs)
typedef __attribute__((ext_vector_type(4))) float f32x4;    // MFMA acc

__device__ __forceinline__ uint16_t f2bf(float f) {
  uint32_t u = __float_as_uint(f);
  u += 0x7FFF + ((u >> 16) & 1);          // RNE
  return (uint16_t)(u >> 16);
}
__device__ __forceinline__ float bf2f(uint16_t h) {
  return __uint_as_float(((uint32_t)h) << 16);
}
__device__ __forceinline__ float gelu_exact(float v) {
  return 0.5f * v * (1.0f + erff(v * 0.70710678118654752f));
}
__device__ __forceinline__ f32x4 mfma16(short8 a, short8 b, f32x4 c) {
  return __builtin_amdgcn_mfma_f32_16x16x32_bf16(a, b, c, 0, 0, 0);
}

#define GLD16(gsrc, ldst) __builtin_amdgcn_global_load_lds(                    \
    (const __attribute__((address_space(1))) void*)(gsrc),                     \
    (__attribute__((address_space(3))) void*)(ldst), 16, 0, 0)

// ---------------- split f32 -> bf16 hi/lo ----------------
__global__ void k_split(const float* __restrict__ src, uint16_t* __restrict__ h,
                        uint16_t* __restrict__ l, int n4) {
  int i = blockIdx.x * blockDim.x + threadIdx.x;
  if (i >= n4) return;
  const float4 v = ((const float4*)src)[i];
  float vv[4] = {v.x, v.y, v.z, v.w};
  ushort4 hh, ll;
  uint16_t* hp = (uint16_t*)&hh;
  uint16_t* lp = (uint16_t*)&ll;
#pragma unroll
  for (int e = 0; e < 4; ++e) {
    uint16_t hb = f2bf(vv[e]);
    hp[e] = hb;
    lp[e] = f2bf(vv[e] - bf2f(hb));
  }
  ((ushort4*)h)[i] = hh;
  ((ushort4*)l)[i] = ll;
}

// ---------------- row-normalize adj -> bf16 ----------------
__global__ void k_norm_adj(const float* __restrict__ adj, uint16_t* __restrict__ An) {
  const int r = blockIdx.x;       // 0..32767
  const int t = threadIdx.x;      // 0..255
  const float* row = adj + (size_t)r * 1024;
  const float4 v = *(const float4*)(row + t * 4);
  float s = v.x + v.y + v.z + v.w;
#pragma unroll
  for (int off = 32; off; off >>= 1) s += __shfl_down(s, off);
  __shared__ float ws[4];
  if ((t & 63) == 0) ws[t >> 6] = s;
  __syncthreads();
  const float deg = ws[0] + ws[1] + ws[2] + ws[3];
  const float dinv = (deg != 0.f) ? 1.f / deg : 0.f;
  ushort4 o;
  uint16_t* op = (uint16_t*)&o;
  float vv[4] = {v.x, v.y, v.z, v.w};
#pragma unroll
  for (int e = 0; e < 4; ++e) op[e] = f2bf(vv[e] * dinv);
  *(ushort4*)(An + (size_t)r * 1024 + t * 4) = o;
}

// ---------------- linear: Yt = (X @ W^T + b), split, transposed ----------------
__global__ __launch_bounds__(256) void k_linear(
    const uint16_t* __restrict__ Xh, const uint16_t* __restrict__ Xl,
    const uint16_t* __restrict__ Wh, const uint16_t* __restrict__ Wl,
    const float* __restrict__ bias,
    uint16_t* __restrict__ Yth, uint16_t* __restrict__ Ytl) {
  __shared__ __align__(16) uint8_t smem[32768];  // Ah|Al|Wh|Wl tiles, 8KB each
  const int tid = threadIdx.x;
  const int lane = tid & 63;
  const int wave = tid >> 6;
  const int wr = wave >> 1, wc = wave & 1;
  const int m0 = blockIdx.x * 128;   // global row (b*1024+node)
  const int n0 = blockIdx.y * 128;   // out-feature
  const int lm = lane & 15, g = lane >> 4;
  const int srow = lane >> 2;
  const int skof = (lane & 3) * 8;

  f32x4 acc[4][4] = {};

  for (int kt = 0; kt < 8; ++kt) {
    const int k0 = kt * 32;
    __syncthreads();
#pragma unroll
    for (int j = 0; j < 8; ++j) {
      const int c = j * 4 + wave;    // 0..31
      const int sub = c & 7, which = c >> 3;
      const int row = sub * 16 + srow;
      const uint16_t* src;
      if (which == 0)      src = Xh + (size_t)(m0 + row) * 256 + k0 + skof;
      else if (which == 1) src = Xl + (size_t)(m0 + row) * 256 + k0 + skof;
      else if (which == 2) src = Wh + (size_t)(n0 + row) * 256 + k0 + skof;
      else                 src = Wl + (size_t)(n0 + row) * 256 + k0 + skof;
      GLD16(src, smem + c * 1024);
    }
    asm volatile("s_waitcnt vmcnt(0)" ::: "memory");
    __syncthreads();

    const uint8_t* Ahs = smem;
    const uint8_t* Als = smem + 8192;
    const uint8_t* Bhs = smem + 16384;
    const uint8_t* Bls = smem + 24576;
    short8 ah[4], al[4], bh[4], bl[4];
#pragma unroll
    for (int f = 0; f < 4; ++f) {
      ah[f] = *(const short8*)(Ahs + (wr * 64 + f * 16 + lm) * 64 + g * 16);
      al[f] = *(const short8*)(Als + (wr * 64 + f * 16 + lm) * 64 + g * 16);
      bh[f] = *(const short8*)(Bhs + (wc * 64 + f * 16 + lm) * 64 + g * 16);
      bl[f] = *(const short8*)(Bls + (wc * 64 + f * 16 + lm) * 64 + g * 16);
    }
#pragma unroll
    for (int fm = 0; fm < 4; ++fm)
#pragma unroll
      for (int fn = 0; fn < 4; ++fn) {
        acc[fm][fn] = mfma16(ah[fm], bh[fn], acc[fm][fn]);
        acc[fm][fn] = mfma16(ah[fm], bl[fn], acc[fm][fn]);
        acc[fm][fn] = mfma16(al[fm], bh[fn], acc[fm][fn]);
      }
  }

#pragma unroll
  for (int fn = 0; fn < 4; ++fn) {
    const int n = n0 + wc * 64 + fn * 16 + lm;
    const float bv = bias[n];
#pragma unroll
    for (int fm = 0; fm < 4; ++fm) {
      const int mg = m0 + wr * 64 + fm * 16 + g * 4;
      const int bb = mg >> 10, node = mg & 1023;
      ushort4 hh, ll;
      uint16_t* hp = (uint16_t*)&hh;
      uint16_t* lp = (uint16_t*)&ll;
#pragma unroll
      for (int e = 0; e < 4; ++e) {
        const float v = acc[fm][fn][e] + bv;
        const uint16_t hb = f2bf(v);
        hp[e] = hb;
        lp[e] = f2bf(v - bf2f(hb));
      }
      const size_t o = ((size_t)(bb * 256 + n)) * 1024 + node;
      *(ushort4*)(Yth + o) = hh;
      *(ushort4*)(Ytl + o) = ll;
    }
  }
}

// ---------------- aggregate: Z = An[b] @ Y, mask, gelu ----------------
// 4-phase counted-vmcnt pipeline. BM=128, BN=256 (full feat), BK=32.
// LDS: 3 buffers x {A 8KB | Bh 16KB | Bl 16KB} = 120KB, depth-2 prefetch.
// 8 waves as 2(M) x 4(N); per-wave 64x64 out = 4x4 fragments.
#define PH_BAR() asm volatile("s_barrier" ::: "memory")
#define MFMA8(B0, B1, FN0, FN1)                                                \
  PH_BAR();                                                                    \
  __builtin_amdgcn_s_setprio(1);                                               \
  acc[0][FN0] = mfma16(a[0], B0, acc[0][FN0]);                                 \
  acc[1][FN0] = mfma16(a[1], B0, acc[1][FN0]);                                 \
  acc[2][FN0] = mfma16(a[2], B0, acc[2][FN0]);                                 \
  acc[3][FN0] = mfma16(a[3], B0, acc[3][FN0]);                                 \
  acc[0][FN1] = mfma16(a[0], B1, acc[0][FN1]);                                 \
  acc[1][FN1] = mfma16(a[1], B1, acc[1][FN1]);                                 \
  acc[2][FN1] = mfma16(a[2], B1, acc[2][FN1]);                                 \
  acc[3][FN1] = mfma16(a[3], B1, acc[3][FN1]);                                 \
  __builtin_amdgcn_s_setprio(0);                                               \
  PH_BAR();

template <bool LAST>
__global__ __launch_bounds__(512, 2) void k_agg(
    const uint16_t* __restrict__ An,
    const uint16_t* __restrict__ Yth, const uint16_t* __restrict__ Ytl,
    const float* __restrict__ mask,
    uint16_t* __restrict__ Xh, uint16_t* __restrict__ Xl,
    float* __restrict__ out) {
  __shared__ __align__(16) uint8_t smem[122880];   // 3 x 40960
  const int tid = threadIdx.x;
  const int lane = tid & 63;
  const int wave = tid >> 6;            // 0..7
  const int wr = wave >> 2, wc = wave & 3;
  const int id = blockIdx.x;            // 0..255
  const int swz = (id & 7) * 32 + (id >> 3);   // XCD-chunked (bijective, 256%8==0)
  const int b = swz >> 3;               // batch
  const int m0 = (swz & 7) * 128;       // node block
  const int lm = lane & 15, g = lane >> 4;
  const int srow = wave * 16 + (lane >> 2);    // staging row this thread covers
  const int skof = (lane & 3) * 8;             // staging k-elem offset

  // per-thread global staging bases (add k0 per tile)
  const uint16_t* Asrc  = An  + (size_t)b * (1024 * 1024) + (size_t)(m0 + srow) * 1024 + skof;
  const uint16_t* Yhsrc = Yth + (size_t)b * (256 * 1024) + (size_t)srow * 1024 + skof;
  const uint16_t* Ylsrc = Ytl + (size_t)b * (256 * 1024) + (size_t)srow * 1024 + skof;

  // fragment read offsets (byte, within region)
  const int aoff = (wr * 64 + lm) * 64 + g * 16;   // + fm*1024
  const int boff = (wc * 64 + lm) * 64 + g * 16;   // + fn*1024

  f32x4 acc[4][4] = {};

  // prologue: stage tiles 0 and 1 (5 issues each, in order)
#pragma unroll
  for (int tt = 0; tt < 2; ++tt) {
    uint8_t* sb = smem + tt * 40960;
    const int k0 = tt * 32;
    GLD16(Asrc + k0,           sb + wave * 1024);
    GLD16(Yhsrc + k0,          sb + 8192  + wave * 1024);
    GLD16(Yhsrc + 131072 + k0, sb + 16384 + wave * 1024);
    GLD16(Ylsrc + k0,          sb + 24576 + wave * 1024);
    GLD16(Ylsrc + 131072 + k0, sb + 32768 + wave * 1024);
  }

  int pc = 0, ps = 2;   // current buf, stage buf ((t+2)%3)
#pragma unroll 1
  for (int t = 0; t < 32; ++t) {
    const uint8_t* buf = smem + pc * 40960;
    uint8_t* sb = smem + ps * 40960;
    const int k0s = (t + 2) * 32;
    const bool st = (t < 30);
    if (t < 31) { asm volatile("s_waitcnt vmcnt(5)" ::: "memory"); }
    else        { asm volatile("s_waitcnt vmcnt(0)" ::: "memory"); }
    PH_BAR();

    const uint8_t* A_s  = buf;
    const uint8_t* Bh_s = buf + 8192;
    const uint8_t* Bl_s = buf + 24576;
    short8 a[4], b0, b1;

    // ---- phase 0: hi-term, fn 0,1 ----
    a[0] = *(const short8*)(A_s + aoff);
    a[1] = *(const short8*)(A_s + aoff + 1024);
    a[2] = *(const short8*)(A_s + aoff + 2048);
    a[3] = *(const short8*)(A_s + aoff + 3072);
    b0 = *(const short8*)(Bh_s + boff);
    b1 = *(const short8*)(Bh_s + boff + 1024);
    if (st) GLD16(Asrc + k0s, sb + wave * 1024);
    MFMA8(b0, b1, 0, 1);

    // ---- phase 1: hi-term, fn 2,3 ----
    b0 = *(const short8*)(Bh_s + boff + 2048);
    b1 = *(const short8*)(Bh_s + boff + 3072);
    if (st) GLD16(Yhsrc + k0s, sb + 8192 + wave * 1024);
    MFMA8(b0, b1, 2, 3);

    // ---- phase 2: lo-term, fn 0,1 ----
    b0 = *(const short8*)(Bl_s + boff);
    b1 = *(const short8*)(Bl_s + boff + 1024);
    if (st) GLD16(Yhsrc + 131072 + k0s, sb + 16384 + wave * 1024);
    MFMA8(b0, b1, 0, 1);

    // ---- phase 3: lo-term, fn 2,3 ----
    b0 = *(const short8*)(Bl_s + boff + 2048);
    b1 = *(const short8*)(Bl_s + boff + 3072);
    if (st) {
      GLD16(Ylsrc + k0s,          sb + 24576 + wave * 1024);
      GLD16(Ylsrc + 131072 + k0s, sb + 32768 + wave * 1024);
    }
    MFMA8(b0, b1, 2, 3);

    pc = (pc == 2) ? 0 : pc + 1;
    ps = (ps == 2) ? 0 : ps + 1;
  }

  // epilogue: mask (per out-node), exact gelu, store
  const float* mb = mask + b * 1024;
#pragma unroll
  for (int fm = 0; fm < 4; ++fm) {
    const int m = m0 + wr * 64 + fm * 16 + g * 4;
    float mk[4];
#pragma unroll
    for (int e = 0; e < 4; ++e) mk[e] = mb[m + e];
#pragma unroll
    for (int fn = 0; fn < 4; ++fn) {
      const int n = wc * 64 + fn * 16 + lm;
#pragma unroll
      for (int e = 0; e < 4; ++e) {
        const float v = gelu_exact(acc[fm][fn][e] * mk[e]);
        const size_t o = ((size_t)(b * 1024 + m + e)) * 256 + n;
        if (LAST) {
          out[o] = v;
        } else {
          const uint16_t hb = f2bf(v);
          Xh[o] = hb;
          Xl[o] = f2bf(v - bf2f(hb));
        }
      }
    }
  }
}

extern "C" void kernel_launch(void* const* d_in, const int* in_sizes, int n_in,
                              void* d_out, int out_size, void* d_ws, size_t ws_size,
                              hipStream_t stream) {
  const float* x    = (const float*)d_in[0];
  const float* mask = (const float*)d_in[1];
  const float* adj  = (const float*)d_in[2];
  const float* W[3]  = {(const float*)d_in[3], (const float*)d_in[5], (const float*)d_in[7]};
  const float* bs[3] = {(const float*)d_in[4], (const float*)d_in[6], (const float*)d_in[8]};

  uint8_t* ws = (uint8_t*)d_ws;
  uint16_t* An  = (uint16_t*)(ws);                    // 67108864 B
  uint16_t* Xh  = (uint16_t*)(ws + 67108864);         // 16777216
  uint16_t* Xl  = (uint16_t*)(ws + 83886080);         // 16777216
  uint16_t* Yth = (uint16_t*)(ws + 100663296);        // 16777216
  uint16_t* Ytl = (uint16_t*)(ws + 117440512);        // 16777216
  uint16_t* Wh  = (uint16_t*)(ws + 134217728);        // 393216
  uint16_t* Wl  = (uint16_t*)(ws + 134610944);        // 393216

  k_split<<<dim3(8192), 256, 0, stream>>>(x, Xh, Xl, 2097152);
  for (int i = 0; i < 3; ++i)
    k_split<<<dim3(64), 256, 0, stream>>>(W[i], Wh + i * 65536, Wl + i * 65536, 16384);
  k_norm_adj<<<dim3(32768), 256, 0, stream>>>(adj, An);

  for (int l = 0; l < 3; ++l) {
    k_linear<<<dim3(256, 2), 256, 0, stream>>>(Xh, Xl, Wh + l * 65536, Wl + l * 65536,
                                               bs[l], Yth, Ytl);
    if (l < 2)
      k_agg<false><<<dim3(256), 512, 0, stream>>>(An, Yth, Ytl, mask, Xh, Xl, nullptr);
    else
      k_agg<true><<<dim3(256), 512, 0, stream>>>(An, Yth, Ytl, mask, nullptr, nullptr,
                                                 (float*)d_out);
  }
}

// Round 3
// 254.445 us; speedup vs baseline: 1.2951x; 1.0104x over previous
//
#include <hip/hip_runtime.h>
#include <stdint.h>

// GraphConvLayer: 3x { x = X@W^T + b; x = Ahat @ x; x *= mask; x = gelu(x) }
// B=32, N=1024, D=256. Split-bf16 (hi/lo) MFMA for f32-grade accuracy.
// R3: k_agg = 128x256 tile, reg-staged double-buffer (T14), 1 barrier/tile,
//     2 reg-sets depth, per-wave 64x64 (32 MFMA / 12 ds_read per tile).

typedef __attribute__((ext_vector_type(8))) short short8;   // 8 bf16 (4 VGPRs)
typedef __attribute__((ext_vector_type(4))) float f32x4;    // MFMA acc

__device__ __forceinline__ uint16_t f2bf(float f) {
  uint32_t u = __float_as_uint(f);
  u += 0x7FFF + ((u >> 16) & 1);          // RNE
  return (uint16_t)(u >> 16);
}
__device__ __forceinline__ float bf2f(uint16_t h) {
  return __uint_as_float(((uint32_t)h) << 16);
}
__device__ __forceinline__ float gelu_exact(float v) {
  return 0.5f * v * (1.0f + erff(v * 0.70710678118654752f));
}
__device__ __forceinline__ f32x4 mfma16(short8 a, short8 b, f32x4 c) {
  return __builtin_amdgcn_mfma_f32_16x16x32_bf16(a, b, c, 0, 0, 0);
}

#define GLD16(gsrc, ldst) __builtin_amdgcn_global_load_lds(                    \
    (const __attribute__((address_space(1))) void*)(gsrc),                     \
    (__attribute__((address_space(3))) void*)(ldst), 16, 0, 0)

// ---------------- split f32 -> bf16 hi/lo ----------------
__global__ void k_split(const float* __restrict__ src, uint16_t* __restrict__ h,
                        uint16_t* __restrict__ l, int n4) {
  int i = blockIdx.x * blockDim.x + threadIdx.x;
  if (i >= n4) return;
  const float4 v = ((const float4*)src)[i];
  float vv[4] = {v.x, v.y, v.z, v.w};
  ushort4 hh, ll;
  uint16_t* hp = (uint16_t*)&hh;
  uint16_t* lp = (uint16_t*)&ll;
#pragma unroll
  for (int e = 0; e < 4; ++e) {
    uint16_t hb = f2bf(vv[e]);
    hp[e] = hb;
    lp[e] = f2bf(vv[e] - bf2f(hb));
  }
  ((ushort4*)h)[i] = hh;
  ((ushort4*)l)[i] = ll;
}

// ---------------- row-normalize adj -> bf16 ----------------
__global__ void k_norm_adj(const float* __restrict__ adj, uint16_t* __restrict__ An) {
  const int r = blockIdx.x;       // 0..32767
  const int t = threadIdx.x;      // 0..255
  const float* row = adj + (size_t)r * 1024;
  const float4 v = *(const float4*)(row + t * 4);
  float s = v.x + v.y + v.z + v.w;
#pragma unroll
  for (int off = 32; off; off >>= 1) s += __shfl_down(s, off);
  __shared__ float ws[4];
  if ((t & 63) == 0) ws[t >> 6] = s;
  __syncthreads();
  const float deg = ws[0] + ws[1] + ws[2] + ws[3];
  const float dinv = (deg != 0.f) ? 1.f / deg : 0.f;
  ushort4 o;
  uint16_t* op = (uint16_t*)&o;
  float vv[4] = {v.x, v.y, v.z, v.w};
#pragma unroll
  for (int e = 0; e < 4; ++e) op[e] = f2bf(vv[e] * dinv);
  *(ushort4*)(An + (size_t)r * 1024 + t * 4) = o;
}

// ---------------- linear: Yt = (X @ W^T + b), split, transposed ----------------
__global__ __launch_bounds__(256) void k_linear(
    const uint16_t* __restrict__ Xh, const uint16_t* __restrict__ Xl,
    const uint16_t* __restrict__ Wh, const uint16_t* __restrict__ Wl,
    const float* __restrict__ bias,
    uint16_t* __restrict__ Yth, uint16_t* __restrict__ Ytl) {
  __shared__ __align__(16) uint8_t smem[32768];  // Ah|Al|Wh|Wl tiles, 8KB each
  const int tid = threadIdx.x;
  const int lane = tid & 63;
  const int wave = tid >> 6;
  const int wr = wave >> 1, wc = wave & 1;
  const int m0 = blockIdx.x * 128;   // global row (b*1024+node)
  const int n0 = blockIdx.y * 128;   // out-feature
  const int lm = lane & 15, g = lane >> 4;
  const int srow = lane >> 2;
  const int skof = (lane & 3) * 8;

  f32x4 acc[4][4] = {};

  for (int kt = 0; kt < 8; ++kt) {
    const int k0 = kt * 32;
    __syncthreads();
#pragma unroll
    for (int j = 0; j < 8; ++j) {
      const int c = j * 4 + wave;    // 0..31
      const int sub = c & 7, which = c >> 3;
      const int row = sub * 16 + srow;
      const uint16_t* src;
      if (which == 0)      src = Xh + (size_t)(m0 + row) * 256 + k0 + skof;
      else if (which == 1) src = Xl + (size_t)(m0 + row) * 256 + k0 + skof;
      else if (which == 2) src = Wh + (size_t)(n0 + row) * 256 + k0 + skof;
      else                 src = Wl + (size_t)(n0 + row) * 256 + k0 + skof;
      GLD16(src, smem + c * 1024);
    }
    asm volatile("s_waitcnt vmcnt(0)" ::: "memory");
    __syncthreads();

    const uint8_t* Ahs = smem;
    const uint8_t* Als = smem + 8192;
    const uint8_t* Bhs = smem + 16384;
    const uint8_t* Bls = smem + 24576;
    short8 ah[4], al[4], bh[4], bl[4];
#pragma unroll
    for (int f = 0; f < 4; ++f) {
      ah[f] = *(const short8*)(Ahs + (wr * 64 + f * 16 + lm) * 64 + g * 16);
      al[f] = *(const short8*)(Als + (wr * 64 + f * 16 + lm) * 64 + g * 16);
      bh[f] = *(const short8*)(Bhs + (wc * 64 + f * 16 + lm) * 64 + g * 16);
      bl[f] = *(const short8*)(Bls + (wc * 64 + f * 16 + lm) * 64 + g * 16);
    }
#pragma unroll
    for (int fm = 0; fm < 4; ++fm)
#pragma unroll
      for (int fn = 0; fn < 4; ++fn) {
        acc[fm][fn] = mfma16(ah[fm], bh[fn], acc[fm][fn]);
        acc[fm][fn] = mfma16(ah[fm], bl[fn], acc[fm][fn]);
        acc[fm][fn] = mfma16(al[fm], bh[fn], acc[fm][fn]);
      }
  }

#pragma unroll
  for (int fn = 0; fn < 4; ++fn) {
    const int n = n0 + wc * 64 + fn * 16 + lm;
    const float bv = bias[n];
#pragma unroll
    for (int fm = 0; fm < 4; ++fm) {
      const int mg = m0 + wr * 64 + fm * 16 + g * 4;
      const int bb = mg >> 10, node = mg & 1023;
      ushort4 hh, ll;
      uint16_t* hp = (uint16_t*)&hh;
      uint16_t* lp = (uint16_t*)&ll;
#pragma unroll
      for (int e = 0; e < 4; ++e) {
        const float v = acc[fm][fn][e] + bv;
        const uint16_t hb = f2bf(v);
        hp[e] = hb;
        lp[e] = f2bf(v - bf2f(hb));
      }
      const size_t o = ((size_t)(bb * 256 + n)) * 1024 + node;
      *(ushort4*)(Yth + o) = hh;
      *(ushort4*)(Ytl + o) = ll;
    }
  }
}

// ---------------- aggregate: Z = An[b] @ Y, mask, gelu ----------------
// Tile 128(M) x 256(N=all feats) x BK=32. 8 waves (2M x 4N), per-wave 64x64.
// Reg-staged double-buffer: 2 reg sets (tiles t+1, t+2 in flight), 2 LDS bufs.
// LDS buffer layout: [A 8KB | Bh 16KB | Bl 16KB] = 40KB; rows 64B wide.
#define TILE_BAR()                                                             \
  asm volatile("s_waitcnt lgkmcnt(0)" ::: "memory");                           \
  __builtin_amdgcn_sched_barrier(0);                                           \
  __builtin_amdgcn_s_barrier();

#define ISSUE(VA, VB1, VB2, VB3, VB4, KO)                                      \
  VA  = *(const int4*)(gA  + (KO));                                            \
  VB1 = *(const int4*)(gB1 + (KO));                                            \
  VB2 = *(const int4*)(gB2 + (KO));                                            \
  VB3 = *(const int4*)(gB3 + (KO));                                            \
  VB4 = *(const int4*)(gB4 + (KO));

#define DSW(BUF, VA, VB1, VB2, VB3, VB4)                                       \
  *(int4*)((BUF) + tid * 16)         = VA;                                     \
  *(int4*)((BUF) + 8192  + tid * 16) = VB1;                                    \
  *(int4*)((BUF) + 16384 + tid * 16) = VB2;                                    \
  *(int4*)((BUF) + 24576 + tid * 16) = VB3;                                    \
  *(int4*)((BUF) + 32768 + tid * 16) = VB4;

#define COMPUTE(BUF)                                                           \
  {                                                                            \
    const uint8_t* bb_ = (BUF);                                                \
    short8 af[4], bhf[4], blf[4];                                              \
    _Pragma("unroll")                                                          \
    for (int f = 0; f < 4; ++f) {                                              \
      af[f]  = *(const short8*)(bb_ + aoff + f * 1024);                        \
      bhf[f] = *(const short8*)(bb_ + 8192 + boff + f * 1024);                 \
      blf[f] = *(const short8*)(bb_ + 24576 + boff + f * 1024);                \
    }                                                                          \
    __builtin_amdgcn_s_setprio(1);                                             \
    _Pragma("unroll")                                                          \
    for (int fm = 0; fm < 4; ++fm)                                             \
      _Pragma("unroll")                                                        \
      for (int fn = 0; fn < 4; ++fn) {                                         \
        acc[fm][fn] = mfma16(af[fm], bhf[fn], acc[fm][fn]);                    \
        acc[fm][fn] = mfma16(af[fm], blf[fn], acc[fm][fn]);                    \
      }                                                                        \
    __builtin_amdgcn_s_setprio(0);                                             \
  }

template <bool LAST>
__global__ __launch_bounds__(512, 1) void k_agg(
    const uint16_t* __restrict__ An,
    const uint16_t* __restrict__ Yth, const uint16_t* __restrict__ Ytl,
    const float* __restrict__ mask,
    uint16_t* __restrict__ Xh, uint16_t* __restrict__ Xl,
    float* __restrict__ out) {
  __shared__ __align__(16) uint8_t smem[81920];   // 2 x 40960
  const int tid = threadIdx.x;
  const int lane = tid & 63;
  const int wave = tid >> 6;            // 0..7
  const int wr = wave >> 2, wc = wave & 3;        // 2(M) x 4(N)
  const int id = blockIdx.x;            // 0..255
  const int swz = (id & 7) * 32 + (id >> 3);      // XCD-chunked (bijective)
  const int b = swz >> 3;               // batch
  const int m0 = (swz & 7) * 128;       // node block
  const int lm = lane & 15, g = lane >> 4;

  // per-thread staging sources (each thread: 5 x 16B per tile; advance by KO elems)
  const uint16_t* Yhb = Yth + (size_t)b * (256 * 1024);
  const uint16_t* Ylb = Ytl + (size_t)b * (256 * 1024);
  const uint16_t* gA  = An + (size_t)b * (1024 * 1024) + (size_t)(m0 + (tid >> 2)) * 1024 + (tid & 3) * 8;
  const uint16_t* gB1 = Yhb + (size_t)(tid >> 2) * 1024 + (tid & 3) * 8;          // feat 0-127
  const uint16_t* gB2 = Yhb + (size_t)(128 + (tid >> 2)) * 1024 + (tid & 3) * 8;  // feat 128-255
  const uint16_t* gB3 = Ylb + (size_t)(tid >> 2) * 1024 + (tid & 3) * 8;
  const uint16_t* gB4 = Ylb + (size_t)(128 + (tid >> 2)) * 1024 + (tid & 3) * 8;

  // fragment read offsets (byte, region-local)
  const int aoff = (wr * 64 + lm) * 64 + g * 16;   // + fm*1024
  const int boff = (wc * 64 + lm) * 64 + g * 16;   // + fn*1024

  uint8_t* buf0 = smem;
  uint8_t* buf1 = smem + 40960;

  f32x4 acc[4][4] = {};
  int4 s0a, s0b1, s0b2, s0b3, s0b4;    // reg set 0 (even tiles' prefetch)
  int4 s1a, s1b1, s1b2, s1b3, s1b4;    // reg set 1 (odd tiles' prefetch)

  // prologue: load tiles 0,1 into regs; write tile0 -> buf0
  ISSUE(s0a, s0b1, s0b2, s0b3, s0b4, 0);
  ISSUE(s1a, s1b1, s1b2, s1b3, s1b4, 32);
  DSW(buf0, s0a, s0b1, s0b2, s0b3, s0b4);
  TILE_BAR();

  // main loop: t = 0..29, unroll-2 for static reg-set indexing.
  // even t: issue s0 <- tile t+2; compute buf0 (tile t); write s1 (t+1) -> buf1
  // odd  t: issue s1 <- tile t+3... (symmetric)
#pragma unroll 1
  for (int tp = 0; tp < 15; ++tp) {
    const int ke = (tp * 2 + 2) * 32;   // tile t+2 for even body
    ISSUE(s0a, s0b1, s0b2, s0b3, s0b4, ke);
    COMPUTE(buf0);
    DSW(buf1, s1a, s1b1, s1b2, s1b3, s1b4);
    TILE_BAR();
    const int ko = (tp * 2 + 3) * 32;
    ISSUE(s1a, s1b1, s1b2, s1b3, s1b4, ko);
    COMPUTE(buf1);
    DSW(buf0, s0a, s0b1, s0b2, s0b3, s0b4);
    TILE_BAR();
  }
  // t=30: compute buf0 (tile 30); write s1 (tile 31) -> buf1
  COMPUTE(buf0);
  DSW(buf1, s1a, s1b1, s1b2, s1b3, s1b4);
  TILE_BAR();
  // t=31: compute buf1 (tile 31)
  COMPUTE(buf1);

  // epilogue: mask (per out-node), exact gelu, store
  const float* mb = mask + b * 1024;
#pragma unroll
  for (int fm = 0; fm < 4; ++fm) {
    const int m = m0 + wr * 64 + fm * 16 + g * 4;
    float mk[4];
#pragma unroll
    for (int e = 0; e < 4; ++e) mk[e] = mb[m + e];
#pragma unroll
    for (int fn = 0; fn < 4; ++fn) {
      const int n = wc * 64 + fn * 16 + lm;
#pragma unroll
      for (int e = 0; e < 4; ++e) {
        const float v = gelu_exact(acc[fm][fn][e] * mk[e]);
        const size_t o = ((size_t)(b * 1024 + m + e)) * 256 + n;
        if (LAST) {
          out[o] = v;
        } else {
          const uint16_t hb = f2bf(v);
          Xh[o] = hb;
          Xl[o] = f2bf(v - bf2f(hb));
        }
      }
    }
  }
}

extern "C" void kernel_launch(void* const* d_in, const int* in_sizes, int n_in,
                              void* d_out, int out_size, void* d_ws, size_t ws_size,
                              hipStream_t stream) {
  const float* x    = (const float*)d_in[0];
  const float* mask = (const float*)d_in[1];
  const float* adj  = (const float*)d_in[2];
  const float* W[3]  = {(const float*)d_in[3], (const float*)d_in[5], (const float*)d_in[7]};
  const float* bs[3] = {(const float*)d_in[4], (const float*)d_in[6], (const float*)d_in[8]};

  uint8_t* ws = (uint8_t*)d_ws;
  uint16_t* An  = (uint16_t*)(ws);                    // 67108864 B
  uint16_t* Xh  = (uint16_t*)(ws + 67108864);         // 16777216
  uint16_t* Xl  = (uint16_t*)(ws + 83886080);         // 16777216
  uint16_t* Yth = (uint16_t*)(ws + 100663296);        // 16777216
  uint16_t* Ytl = (uint16_t*)(ws + 117440512);        // 16777216
  uint16_t* Wh  = (uint16_t*)(ws + 134217728);        // 393216
  uint16_t* Wl  = (uint16_t*)(ws + 134610944);        // 393216

  k_split<<<dim3(8192), 256, 0, stream>>>(x, Xh, Xl, 2097152);
  for (int i = 0; i < 3; ++i)
    k_split<<<dim3(64), 256, 0, stream>>>(W[i], Wh + i * 65536, Wl + i * 65536, 16384);
  k_norm_adj<<<dim3(32768), 256, 0, stream>>>(adj, An);

  for (int l = 0; l < 3; ++l) {
    k_linear<<<dim3(256, 2), 256, 0, stream>>>(Xh, Xl, Wh + l * 65536, Wl + l * 65536,
                                               bs[l], Yth, Ytl);
    if (l < 2)
      k_agg<false><<<dim3(256), 512, 0, stream>>>(An, Yth, Ytl, mask, Xh, Xl, nullptr);
    else
      k_agg<true><<<dim3(256), 512, 0, stream>>>(An, Yth, Ytl, mask, nullptr, nullptr,
                                                 (float*)d_out);
  }
}